// Round 13
// baseline (242.871 us; speedup 1.0000x reference)
//
#include <hip/hip_runtime.h>
#include <hip/hip_bf16.h>

typedef __attribute__((ext_vector_type(8))) short s8x;   // 8 bf16 = 4 VGPRs (MFMA A/B frag)
typedef __attribute__((ext_vector_type(4))) float f4x;   // MFMA C/D frag
typedef unsigned short u16;
typedef unsigned int u32;

#define T_ 1024
#define TC_ 2048
#define SCLOG2E 0.1803368801111243f   // 0.125 * log2(e), folded into q-GEMM for exp2 softmax

// fine-grained waitcnt (AITER pattern): wait for all but newest N VMEM ops
#define WAIT_VM(n) asm volatile("s_waitcnt vmcnt(" #n ")" ::: "memory")

__device__ __forceinline__ u16 f2bf(float f) {
    u32 u = __float_as_uint(f);
    return (u16)((u + 0x7fffu + ((u >> 16) & 1u)) >> 16);  // RNE
}

#if defined(__has_builtin)
#if __has_builtin(__builtin_amdgcn_cvt_pk_bf16_f32)
#define HAVE_PK 1
#endif
#if __has_builtin(__builtin_amdgcn_permlane16_swap) && __has_builtin(__builtin_amdgcn_permlane32_swap)
#define HAVE_PLSWAP 1
#endif
#endif

// pack two fp32 -> two bf16 (RNE) in one u32; HW packed cvt when available
__device__ __forceinline__ u32 pack2bf(float a, float b) {
#ifdef HAVE_PK
    typedef __attribute__((ext_vector_type(2))) __bf16 bf2t;
    bf2t r = __builtin_amdgcn_cvt_pk_bf16_f32(a, b);
    u32 u;
    __builtin_memcpy(&u, &r, 4);
    return u;
#else
    return (u32)f2bf(a) | ((u32)f2bf(b) << 16);
#endif
}

// cross-lane 32/16-row swaps (gfx950)
__device__ __forceinline__ void pswap32(u32& a, u32& b) {
#ifdef HAVE_PLSWAP
    typedef __attribute__((ext_vector_type(2))) unsigned int u2x;
    u2x r = __builtin_amdgcn_permlane32_swap(a, b, false, false);
    a = r.x; b = r.y;
#else
    asm("v_permlane32_swap_b32 %0, %1" : "+v"(a), "+v"(b));
#endif
}
__device__ __forceinline__ void pswap16(u32& a, u32& b) {
#ifdef HAVE_PLSWAP
    typedef __attribute__((ext_vector_type(2))) unsigned int u2x;
    u2x r = __builtin_amdgcn_permlane16_swap(a, b, false, false);
    a = r.x; b = r.y;
#else
    asm("v_permlane16_swap_b32 %0, %1" : "+v"(a), "+v"(b));
#endif
}

// async global->LDS, 16B per lane; LDS dst is wave-uniform base + lane*16
__device__ __forceinline__ void gload16(const void* g, void* l) {
    __builtin_amdgcn_global_load_lds((const __attribute__((address_space(1))) u32*)g,
                                     (__attribute__((address_space(3))) u32*)l, 16, 0, 0);
}

// ---- gamma = mean(|W|), 4 weights in one launch ----------------------------
__global__ __launch_bounds__(256) void absmean_k(const float* __restrict__ W0, const float* __restrict__ W1,
                                                 const float* __restrict__ W2, const float* __restrict__ W3,
                                                 float* __restrict__ gsum) {
    int wi = blockIdx.y;
    const float* W = (wi == 0) ? W0 : (wi == 1) ? W1 : (wi == 2) ? W2 : W3;
    const int n4 = (1024 * 1024) / 4;
    float s = 0.f;
    int stride = gridDim.x * blockDim.x;
    for (int i = blockIdx.x * blockDim.x + threadIdx.x; i < n4; i += stride) {
        float4 v = ((const float4*)W)[i];
        s += fabsf(v.x) + fabsf(v.y) + fabsf(v.z) + fabsf(v.w);
    }
#pragma unroll
    for (int off = 32; off; off >>= 1) s += __shfl_down(s, off, 64);
    __shared__ float ps[4];
    if ((threadIdx.x & 63) == 0) ps[threadIdx.x >> 6] = s;
    __syncthreads();
    if (threadIdx.x == 0) atomicAdd(gsum + wi, ps[0] + ps[1] + ps[2] + ps[3]);
}

// ---- merged prep: LN(x)->xn | ctx->bf16 | ternary quantize (one launch) ----
__global__ __launch_bounds__(256) void prep_k(
        const float* __restrict__ x, const float* __restrict__ lng, const float* __restrict__ lnb,
        u16* __restrict__ xn,
        const float* __restrict__ ctx, u16* __restrict__ ctxb,
        const float* __restrict__ W0, const float* __restrict__ W1,
        const float* __restrict__ W2, const float* __restrict__ W3,
        u16* __restrict__ D0, u16* __restrict__ D1, u16* __restrict__ D2, u16* __restrict__ D3,
        const float* __restrict__ gsum) {
    __shared__ float ps[8];
    int bx = blockIdx.x, t = threadIdx.x;
    if (bx < 4096) {                      // LayerNorm row bx
        int row = bx;
        float4 xv = ((const float4*)(x + (long)row * 1024))[t];
        float s = xv.x + xv.y + xv.z + xv.w;
        float s2 = xv.x * xv.x + xv.y * xv.y + xv.z * xv.z + xv.w * xv.w;
#pragma unroll
        for (int off = 32; off; off >>= 1) { s += __shfl_down(s, off, 64); s2 += __shfl_down(s2, off, 64); }
        if ((t & 63) == 0) { ps[t >> 6] = s; ps[4 + (t >> 6)] = s2; }
        __syncthreads();
        float S = ps[0] + ps[1] + ps[2] + ps[3];
        float S2 = ps[4] + ps[5] + ps[6] + ps[7];
        float mu = S * (1.f / 1024.f);
        float var = S2 * (1.f / 1024.f) - mu * mu;
        float rstd = rsqrtf(var + 1e-5f);
        float4 gv = ((const float4*)lng)[t];
        float4 bv = ((const float4*)lnb)[t];
        uint2 o;
        o.x = pack2bf((xv.x - mu) * rstd * gv.x + bv.x, (xv.y - mu) * rstd * gv.y + bv.y);
        o.y = pack2bf((xv.z - mu) * rstd * gv.z + bv.z, (xv.w - mu) * rstd * gv.w + bv.w);
        ((uint2*)(xn + (long)row * 1024))[t] = o;
    } else if (bx < 12288) {              // cast context
        int i = (bx - 4096) * 256 + t;
        float4 v = ((const float4*)ctx)[i];
        uint2 o = {pack2bf(v.x, v.y), pack2bf(v.z, v.w)};
        ((uint2*)ctxb)[i] = o;
    } else {                              // ternary quantize
        int wi = (bx - 12288) >> 10;
        const float* W = (wi == 0) ? W0 : (wi == 1) ? W1 : (wi == 2) ? W2 : W3;
        u16* D = (wi == 0) ? D0 : (wi == 1) ? D1 : (wi == 2) ? D2 : D3;
        float inv = 1.0f / (gsum[wi] * (1.0f / 1048576.0f) + 1e-5f);
        int i = ((bx - 12288) & 1023) * 256 + t;
        float4 wv = ((const float4*)W)[i];
        uint2 o;
        o.x = pack2bf(fminf(1.f, fmaxf(-1.f, rintf(wv.x * inv))),
                      fminf(1.f, fmaxf(-1.f, rintf(wv.y * inv))));
        o.y = pack2bf(fminf(1.f, fmaxf(-1.f, rintf(wv.z * inv))),
                      fminf(1.f, fmaxf(-1.f, rintf(wv.w * inv))));
        ((uint2*)D)[i] = o;
    }
}

// ---- uber GEMM v10 (best): BK=64, 2x32KB dbuf, 16 unrolled steps -----------
__global__ __launch_bounds__(256) void gemm_fused(
        const u16* __restrict__ xn, const u16* __restrict__ ctxb,
        const u16* __restrict__ wtq, const u16* __restrict__ wtk, const u16* __restrict__ wtv,
        const float* __restrict__ bq, const float* __restrict__ bk, const float* __restrict__ bv,
        const float* __restrict__ gsum,
        u16* __restrict__ qb, u16* __restrict__ kb, u16* __restrict__ vtb) {
    __shared__ __align__(16) char smem[65536];   // 2 x (A0 8K|A1 8K|B0 8K|B1 8K); reused as 32K C^T tile
    int tid = threadIdx.x;
    int w = tid >> 6, l = tid & 63, lq = l & 15, lh = l >> 4;
    int wm = (w >> 1) * 64, wn = (w & 1) * 64;
    int bx = blockIdx.x;
    int xcd = bx & 7;
    int prob, m0, n0, gidx;
    const u16 *A, *Wt;
    const float* bias;
    float sc;
    if (bx < 256) {
        int local = bx >> 3;              // 0..31
        prob = 0; A = xn; Wt = wtq; bias = bq; sc = SCLOG2E; gidx = 0;
        m0 = (xcd * 4 + (local & 3)) * 128;
        n0 = (local >> 2) * 128;
    } else {
        int b = bx - 256;                 // 0..1023
        int local3 = b >> 3;              // 0..127
        int kv = local3 & 1;              // k/v alternate -> share A-tile in L2
        int idx = local3 >> 1;            // 0..63
        prob = 1 + kv; A = ctxb;
        Wt = kv ? wtv : wtk; bias = kv ? bv : bk; sc = 1.0f; gidx = 1 + kv;
        m0 = (xcd * 8 + (idx & 7)) * 128;
        n0 = (idx >> 3) * 128;
    }
    int sp = tid >> 3, ss = tid & 7;
    int st = ss ^ (sp & 7);
    int r0 = sp * 2 + (st >> 2), c0 = st & 3;
    const u16* Ag0 = A + (long)(m0 + r0) * 1024 + c0 * 8;
    const u16* Ag1 = Ag0 + 64 * 1024;
    const u16* Bg0 = Wt + (long)(n0 + r0) * 1024 + c0 * 8;
    const u16* Bg1 = Bg0 + 64 * 1024;
    int aoff[4], boff[4];
#pragma unroll
    for (int i = 0; i < 4; i++) {
        int ar = wm + i * 16 + lq, ap = ar >> 1;
        aoff[i] = ap * 128 + (((((ar & 1) << 2) | lh) ^ (ap & 7)) * 16);
        int br = wn + i * 16 + lq, bp = br >> 1;
        boff[i] = bp * 128 + (((((br & 1) << 2) | lh) ^ (bp & 7)) * 16);
    }
    f4x acc[4][4] = {};
    // stage one BK=64 tile (32KB = 8 gload16): A halves at 0/8K, B at 16K/24K
#define STAGE_G(kt, buf)                                                   \
    {                                                                      \
        char* Ad = smem + (buf) * 32768;                                   \
        gload16(Ag0 + (kt) * 64, Ad + tid * 16);                           \
        gload16(Ag1 + (kt) * 64, Ad + 4096 + tid * 16);                    \
        gload16(Ag0 + (kt) * 64 + 32, Ad + 8192 + tid * 16);               \
        gload16(Ag1 + (kt) * 64 + 32, Ad + 12288 + tid * 16);              \
        gload16(Bg0 + (kt) * 64, Ad + 16384 + tid * 16);                   \
        gload16(Bg1 + (kt) * 64, Ad + 20480 + tid * 16);                   \
        gload16(Bg0 + (kt) * 64 + 32, Ad + 24576 + tid * 16);              \
        gload16(Bg1 + (kt) * 64 + 32, Ad + 28672 + tid * 16);              \
    }
    STAGE_G(0, 0);
    STAGE_G(1, 1);
#pragma unroll
    for (int kt = 0; kt < 16; kt++) {      // fully unrolled: kt compile-time
        if (kt < 15) { WAIT_VM(8); } else { WAIT_VM(0); }
        __builtin_amdgcn_s_barrier();
        const char* Ac = smem + (kt & 1) * 32768;
        const char* Bc = Ac + 16384;
        s8x af[2][4], bfr[2][4];
#pragma unroll
        for (int h = 0; h < 2; h++)
#pragma unroll
            for (int i = 0; i < 4; i++) {
                af[h][i] = *(const s8x*)(Ac + h * 8192 + aoff[i]);
                bfr[h][i] = *(const s8x*)(Bc + h * 8192 + boff[i]);
            }
#pragma unroll
        for (int h = 0; h < 2; h++)
#pragma unroll
            for (int i = 0; i < 4; i++)
#pragma unroll
                for (int j = 0; j < 4; j++)
                    acc[i][j] = __builtin_amdgcn_mfma_f32_16x16x32_bf16(af[h][i], bfr[h][j], acc[i][j], 0, 0, 0);
        __builtin_amdgcn_s_barrier();      // all waves done reading buf kt&1
        if (kt + 2 < 16) STAGE_G(kt + 2, kt & 1);
    }
    float gamma = gsum[gidx] * (1.0f / 1048576.0f) * sc;
    if (prob < 2) {
        u16* outq = (prob == 0) ? qb : kb;
        int tshift = (prob == 0) ? 10 : 11;
        int tmask = (1 << tshift) - 1;
#pragma unroll
        for (int i = 0; i < 4; i++) {
            int gr = m0 + wm + i * 16 + lh * 4;
#pragma unroll
            for (int j = 0; j < 4; j++) {
                int gc = n0 + wn + j * 16 + lq;
                float bb = bias[gc] * sc;
                int h = gc >> 6, d = gc & 63;
#pragma unroll
                for (int r = 0; r < 4; r++) {
                    int row = gr + r;
                    int bidx = row >> tshift, tt = row & tmask;
                    outq[((((long)(bidx * 16 + h)) << tshift) + tt) * 64 + d] = f2bf(acc[i][j][r] * gamma + bb);
                }
            }
        }
    } else {
        // V^T epilogue: C tile -> LDS [col][tt] (swizzled) -> coalesced b128 stores
        __syncthreads();
        char* Ct = smem;
#pragma unroll
        for (int i = 0; i < 4; i++) {
            int tt = wm + i * 16 + lh * 4;
#pragma unroll
            for (int j = 0; j < 4; j++) {
                int c = wn + j * 16 + lq;
                float bb = bias[n0 + c];
                uint2 pk;
                pk.x = pack2bf(acc[i][j][0] * gamma + bb, acc[i][j][1] * gamma + bb);
                pk.y = pack2bf(acc[i][j][2] * gamma + bb, acc[i][j][3] * gamma + bb);
                int slot = (tt >> 3) ^ (c & 15);
                *(uint2*)(Ct + c * 256 + slot * 16 + (tt & 7) * 2) = pk;
            }
        }
        __syncthreads();
        int bb2 = m0 >> 11, t0 = m0 & 2047;
#pragma unroll
        for (int it = 0; it < 8; it++) {
            int e = it * 256 + tid;
            int c = e >> 4, ch = e & 15;
            int slot = ch ^ (c & 15);
            s8x v = *(const s8x*)(Ct + c * 256 + slot * 16);
            int gcg = n0 + c;
            int h = gcg >> 6, d = gcg & 63;
            *(s8x*)(vtb + ((long)((bb2 * 16 + h) * 64 + d)) * TC_ + t0 + ch * 8) = v;
        }
    }
}

// ---- O GEMM v10 (best): out = x + attn @ WoT + bo, BK=64 2x24KB ------------
__global__ __launch_bounds__(256) void gemm_o(const u16* __restrict__ A, const u16* __restrict__ Wt,
                                              const float* __restrict__ bias, const float* __restrict__ gsum,
                                              const float* __restrict__ residual, float* __restrict__ outr) {
    __shared__ __align__(16) char smem[49152];   // 2 x (A0 8K|A1 8K|B0 4K|B1 4K)
    int tid = threadIdx.x;
    int w = tid >> 6, l = tid & 63, lq = l & 15, lh = l >> 4;
    int wm = (w >> 1) * 64, wn = (w & 1) * 32;
    int bx = blockIdx.x;
    int xcd = bx & 7, local = bx >> 3;
    int m0 = (xcd * 4 + (local & 3)) * 128;
    int n0 = (local >> 2) * 64;
    int sp = tid >> 3, ss = tid & 7;
    int st = ss ^ (sp & 7);
    int r0 = sp * 2 + (st >> 2), c0 = st & 3;
    const u16* Ag0 = A + (long)(m0 + r0) * 1024 + c0 * 8;
    const u16* Ag1 = Ag0 + 64 * 1024;
    const u16* Bg0 = Wt + (long)(n0 + r0) * 1024 + c0 * 8;
    int aoff[4], boff[2];
#pragma unroll
    for (int i = 0; i < 4; i++) {
        int ar = wm + i * 16 + lq, ap = ar >> 1;
        aoff[i] = ap * 128 + (((((ar & 1) << 2) | lh) ^ (ap & 7)) * 16);
    }
#pragma unroll
    for (int j = 0; j < 2; j++) {
        int br = wn + j * 16 + lq, bp = br >> 1;
        boff[j] = bp * 128 + (((((br & 1) << 2) | lh) ^ (bp & 7)) * 16);
    }
    f4x acc[4][2] = {};
#define STAGE_O(kt, buf)                                                   \
    {                                                                      \
        char* Ad = smem + (buf) * 24576;                                   \
        gload16(Ag0 + (kt) * 64, Ad + tid * 16);                           \
        gload16(Ag1 + (kt) * 64, Ad + 4096 + tid * 16);                    \
        gload16(Ag0 + (kt) * 64 + 32, Ad + 8192 + tid * 16);               \
        gload16(Ag1 + (kt) * 64 + 32, Ad + 12288 + tid * 16);              \
        gload16(Bg0 + (kt) * 64, Ad + 16384 + tid * 16);                   \
        gload16(Bg0 + (kt) * 64 + 32, Ad + 20480 + tid * 16);              \
    }
    STAGE_O(0, 0);
    STAGE_O(1, 1);
#pragma unroll
    for (int kt = 0; kt < 16; kt++) {
        if (kt < 15) { WAIT_VM(6); } else { WAIT_VM(0); }
        __builtin_amdgcn_s_barrier();
        const char* Ac = smem + (kt & 1) * 24576;
        const char* Bc = Ac + 16384;
        s8x af[2][4], bfr[2][2];
#pragma unroll
        for (int h = 0; h < 2; h++) {
#pragma unroll
            for (int i = 0; i < 4; i++) af[h][i] = *(const s8x*)(Ac + h * 8192 + aoff[i]);
#pragma unroll
            for (int j = 0; j < 2; j++) bfr[h][j] = *(const s8x*)(Bc + h * 4096 + boff[j]);
        }
#pragma unroll
        for (int h = 0; h < 2; h++)
#pragma unroll
            for (int i = 0; i < 4; i++)
#pragma unroll
                for (int j = 0; j < 2; j++)
                    acc[i][j] = __builtin_amdgcn_mfma_f32_16x16x32_bf16(af[h][i], bfr[h][j], acc[i][j], 0, 0, 0);
        __builtin_amdgcn_s_barrier();
        if (kt + 2 < 16) STAGE_O(kt + 2, kt & 1);
    }
    float gamma = gsum[3] * (1.0f / 1048576.0f);
#pragma unroll
    for (int i = 0; i < 4; i++) {
        int gr = m0 + wm + i * 16 + lh * 4;
#pragma unroll
        for (int j = 0; j < 2; j++) {
            int gc = n0 + wn + j * 16 + lq;
            float bb = bias[gc];
#pragma unroll
            for (int r = 0; r < 4; r++) {
                long idx = (long)(gr + r) * 1024 + gc;
                outr[idx] = residual[idx] + acc[i][j][r] * gamma + bb;
            }
        }
    }
}

// ---- flash attention v14: 64 q/block (grid 64x16=1024) on the v12 3-buffer
//      single-barrier pipeline -> 3 blocks/CU (48KB LDS), 1.5x TLP.
//      R11 accounting: wall 53.5us >> max(VALU 27, MFMA 19, LDS 14) per CU
//      -> bubbles; occupancy was GRID-capped at 2 blocks/CU (512 blocks).
//      Halved per-block state (z/oacc/lrun/qf single-qb) fits (256,3)'s
//      168-VGPR cap without spilling (R8's spill was the 128q state at 84).
__global__ __launch_bounds__(256, 3) void attn_k(const u16* __restrict__ qh, const u16* __restrict__ kh,
                                                 const u16* __restrict__ vth, u16* __restrict__ attn) {
    __shared__ __align__(16) char smem[49152];   // 3 x (K 8K | V 8K)
    int tid = threadIdx.x, w = tid >> 6, l = tid & 63, lq = l & 15, lh = l >> 4;
    int bh = blockIdx.x, q0 = blockIdx.y * 64;
    const u16* qp = qh + ((long)bh * T_ + q0) * 64;
    // ---- prologue: Q tile (8KB, swizzled) into buf0, read qf ---------------
#pragma unroll
    for (int i = 0; i < 2; i++) {
        int cid = i * 256 + tid;
        int r = cid >> 3, c = (cid & 7) ^ (r & 7);
        gload16(qp + r * 64 + c * 8, smem + cid * 16);
    }
    __syncthreads();                     // vmcnt(0): Q arrived
    s8x qf[2];                           // B-operand: Q[q=w*16+lq][d=dh*32+lh*8+j]
#pragma unroll
    for (int dh = 0; dh < 2; dh++) {
        int qrow = w * 16 + lq;
        int ch = (dh * 4 + lh) ^ (qrow & 7);
        qf[dh] = *(const s8x*)(smem + qrow * 128 + ch * 16);
    }
    __syncthreads();                     // lgkm(0): Q reads done before overwrite
    // ---- staging pointers (advance per tile) -------------------------------
    int sr = tid >> 3, sc = (tid & 7) ^ ((tid >> 3) & 7);
    const u16* kgA = kh + (long)bh * TC_ * 64 + sr * 64 + sc * 8;
    const u16* kgB = kgA + 2048;                       // +32 rows
    const u16* vgA = vth + (long)bh * 64 * TC_ + (long)sr * TC_ + sc * 8;
    const u16* vgB = vgA + 32 * TC_;
    // ---- LDS read bases: everything else is a 16-bit immediate -------------
    const char* pA = smem + lq * 128 + ((lh ^ (lq & 7)) * 16);
    const char* pB = smem + lq * 128 + (((4 + lh) ^ (lq & 7)) * 16);
#define STAGE3(buf)                                              \
    {                                                            \
        char* Kb = smem + (buf) * 16384;                         \
        gload16(kgA, Kb + tid * 16);                             \
        gload16(kgB, Kb + 4096 + tid * 16);                      \
        gload16(vgA, Kb + 8192 + tid * 16);                      \
        gload16(vgB, Kb + 12288 + tid * 16);                     \
        kgA += 4096; kgB += 4096; vgA += 64; vgB += 64;          \
    }
    // softmax: z[4] -> two bf16 A-frags via cvt_pk + permlane swaps
#define SM1(ZA, PF0, PF1)                                                                                  \
    s8x PF0, PF1;                                                                                          \
    {                                                                                                      \
        u32 w00 = pack2bf(__builtin_amdgcn_exp2f(ZA[0][0]), __builtin_amdgcn_exp2f(ZA[0][1]));             \
        u32 w01 = pack2bf(__builtin_amdgcn_exp2f(ZA[0][2]), __builtin_amdgcn_exp2f(ZA[0][3]));             \
        u32 w10 = pack2bf(__builtin_amdgcn_exp2f(ZA[1][0]), __builtin_amdgcn_exp2f(ZA[1][1]));             \
        u32 w11 = pack2bf(__builtin_amdgcn_exp2f(ZA[1][2]), __builtin_amdgcn_exp2f(ZA[1][3]));             \
        u32 w20 = pack2bf(__builtin_amdgcn_exp2f(ZA[2][0]), __builtin_amdgcn_exp2f(ZA[2][1]));             \
        u32 w21 = pack2bf(__builtin_amdgcn_exp2f(ZA[2][2]), __builtin_amdgcn_exp2f(ZA[2][3]));             \
        u32 w30 = pack2bf(__builtin_amdgcn_exp2f(ZA[3][0]), __builtin_amdgcn_exp2f(ZA[3][1]));             \
        u32 w31 = pack2bf(__builtin_amdgcn_exp2f(ZA[3][2]), __builtin_amdgcn_exp2f(ZA[3][3]));             \
        u32 a0w = w00, a1w = w10; pswap32(a0w, a1w); pswap16(a0w, a1w);                                    \
        u32 b0w = w01, b1w = w11; pswap32(b0w, b1w); pswap16(b0w, b1w);                                    \
        u32 c0w = w20, c1w = w30; pswap32(c0w, c1w); pswap16(c0w, c1w);                                    \
        u32 d0w = w21, d1w = w31; pswap32(d0w, d1w); pswap16(d0w, d1w);                                    \
        u32 pw0[4] = {a0w, b0w, a1w, b1w};                                                                 \
        u32 pw1[4] = {c0w, d0w, c1w, d1w};                                                                 \
        __builtin_memcpy(&PF0, pw0, 16);                                                                   \
        __builtin_memcpy(&PF1, pw1, 16);                                                                   \
    }
    // one pipelined step kt: stage kt+2 (buf SB); PV tile kt (V buf JB, scores
    // ZC); QK tile kt+1 (K buf KB -> ZN). Single barrier; WAIT_VM(0) ~free
    // (loads issued one full compute phase earlier).
#define SUBITER(JB, KB, SB, ZC, ZN, DOSTAGE)                                                               \
    {                                                                                                      \
        WAIT_VM(0);                                                                                        \
        __builtin_amdgcn_s_barrier();                                                                      \
        if (DOSTAGE) STAGE3(SB);                                                                           \
        s8x a0_[4], a1_[4], v0_[4], v1_[4];                                                                \
        _Pragma("unroll") for (int ni = 0; ni < 4; ni++) {                                                 \
            a0_[ni] = *(const s8x*)(pA + (KB) * 16384 + ni * 2048);                                        \
            a1_[ni] = *(const s8x*)(pB + (KB) * 16384 + ni * 2048);                                        \
        }                                                                                                  \
        _Pragma("unroll") for (int nd = 0; nd < 4; nd++) {                                                 \
            v0_[nd] = *(const s8x*)(pA + (JB) * 16384 + 8192 + nd * 2048);                                 \
            v1_[nd] = *(const s8x*)(pB + (JB) * 16384 + 8192 + nd * 2048);                                 \
        }                                                                                                  \
        SM1(ZC, pf0, pf1)                                                                                  \
        __builtin_amdgcn_s_setprio(1);                                                                     \
        _Pragma("unroll") for (int ni = 0; ni < 4; ni++) {                                                 \
            f4x zz = {0.f, 0.f, 0.f, 0.f};                                                                 \
            zz = __builtin_amdgcn_mfma_f32_16x16x32_bf16(a0_[ni], qf[0], zz, 0, 0, 0);                     \
            zz = __builtin_amdgcn_mfma_f32_16x16x32_bf16(a1_[ni], qf[1], zz, 0, 0, 0);                     \
            ZN[ni] = zz;                                                                                   \
        }                                                                                                  \
        lrun = __builtin_amdgcn_mfma_f32_16x16x32_bf16(pf0, ones, lrun, 0, 0, 0);                          \
        lrun = __builtin_amdgcn_mfma_f32_16x16x32_bf16(pf1, ones, lrun, 0, 0, 0);                          \
        _Pragma("unroll") for (int nd = 0; nd < 4; nd++) {                                                 \
            oacc[nd] = __builtin_amdgcn_mfma_f32_16x16x32_bf16(pf0, v0_[nd], oacc[nd], 0, 0, 0);           \
            oacc[nd] = __builtin_amdgcn_mfma_f32_16x16x32_bf16(pf1, v1_[nd], oacc[nd], 0, 0, 0);           \
        }                                                                                                  \
        __builtin_amdgcn_s_setprio(0);                                                                     \
    }
    const s8x ones = {16256, 16256, 16256, 16256, 16256, 16256, 16256, 16256};  // bf16 1.0 x8
    f4x z0[4], z1[4];
    f4x oacc[4] = {};
    f4x lrun = {};
    // ---- pipeline fill: stage tiles 0,1; QK(0) -> z0 -----------------------
    STAGE3(0); STAGE3(1);
    WAIT_VM(4);                          // tile 0 arrived (tile 1 in flight)
    __builtin_amdgcn_s_barrier();
    {
#pragma unroll
        for (int ni = 0; ni < 4; ni++) {
            s8x a0_ = *(const s8x*)(pA + ni * 2048);
            s8x a1_ = *(const s8x*)(pB + ni * 2048);
            f4x zz = {0.f, 0.f, 0.f, 0.f};
            zz = __builtin_amdgcn_mfma_f32_16x16x32_bf16(a0_, qf[0], zz, 0, 0, 0);
            zz = __builtin_amdgcn_mfma_f32_16x16x32_bf16(a1_, qf[1], zz, 0, 0, 0);
            z0[ni] = zz;
        }
    }
    // ---- main loop: kt = 0..29 (period-6: buf%3 x z-parity), stage kt+2 ----
    for (int t = 0; t < 5; t++) {
        SUBITER(0, 1, 2, z0, z1, true)
        SUBITER(1, 2, 0, z1, z0, true)
        SUBITER(2, 0, 1, z0, z1, true)
        SUBITER(0, 1, 2, z1, z0, true)
        SUBITER(1, 2, 0, z0, z1, true)
        SUBITER(2, 0, 1, z1, z0, true)
    }
    // ---- kt=30: compute K(31),V(30); no stage ------------------------------
    SUBITER(0, 1, 2, z0, z1, false)
    // ---- tail kt=31: softmax + PV only (tile31 in buf1) --------------------
    {
        s8x v0_[4], v1_[4];
#pragma unroll
        for (int nd = 0; nd < 4; nd++) {
            v0_[nd] = *(const s8x*)(pA + 1 * 16384 + 8192 + nd * 2048);
            v1_[nd] = *(const s8x*)(pB + 1 * 16384 + 8192 + nd * 2048);
        }
        SM1(z1, pf0, pf1)
        __builtin_amdgcn_s_setprio(1);
        lrun = __builtin_amdgcn_mfma_f32_16x16x32_bf16(pf0, ones, lrun, 0, 0, 0);
        lrun = __builtin_amdgcn_mfma_f32_16x16x32_bf16(pf1, ones, lrun, 0, 0, 0);
#pragma unroll
        for (int nd = 0; nd < 4; nd++) {
            oacc[nd] = __builtin_amdgcn_mfma_f32_16x16x32_bf16(pf0, v0_[nd], oacc[nd], 0, 0, 0);
            oacc[nd] = __builtin_amdgcn_mfma_f32_16x16x32_bf16(pf1, v1_[nd], oacc[nd], 0, 0, 0);
        }
        __builtin_amdgcn_s_setprio(0);
    }
    // ---- epilogue ----------------------------------------------------------
    int b = bh >> 4, h = bh & 15;
#pragma unroll
    for (int r = 0; r < 4; r++) {
        int q = q0 + w * 16 + lh * 4 + r;
        float rcp = 1.f / lrun[r];
#pragma unroll
        for (int nd = 0; nd < 4; nd++)
            attn[((long)(b * T_ + q)) * 1024 + h * 64 + nd * 16 + lq] = f2bf(oacc[nd][r] * rcp);
    }
}

extern "C" void kernel_launch(void* const* d_in, const int* in_sizes, int n_in,
                              void* d_out, int out_size, void* d_ws, size_t ws_size,
                              hipStream_t stream) {
    const float* x   = (const float*)d_in[0];
    const float* ctx = (const float*)d_in[1];
    const float* Wq  = (const float*)d_in[2];
    const float* bq  = (const float*)d_in[3];
    const float* Wk  = (const float*)d_in[4];
    const float* bk  = (const float*)d_in[5];
    const float* Wv  = (const float*)d_in[6];
    const float* bv  = (const float*)d_in[7];
    const float* Wo  = (const float*)d_in[8];
    const float* bo  = (const float*)d_in[9];
    const float* lng = (const float*)d_in[10];
    const float* lnb = (const float*)d_in[11];
    float* out = (float*)d_out;

    char* ws = (char*)d_ws;
    float* gsum = (float*)ws;
    size_t off = 256;
    u16* wtq  = (u16*)(ws + off); off += (size_t)1024 * 1024 * 2;
    u16* wtk  = (u16*)(ws + off); off += (size_t)1024 * 1024 * 2;
    u16* wtv  = (u16*)(ws + off); off += (size_t)1024 * 1024 * 2;
    u16* wto  = (u16*)(ws + off); off += (size_t)1024 * 1024 * 2;
    u16* ctxb = (u16*)(ws + off); off += (size_t)8192 * 1024 * 2;
    u16* xn   = (u16*)(ws + off); off += (size_t)4096 * 1024 * 2;   // reused as attn out
    u16* qb_  = (u16*)(ws + off); off += (size_t)4096 * 1024 * 2;
    u16* kb   = (u16*)(ws + off); off += (size_t)8192 * 1024 * 2;
    u16* vtb  = (u16*)(ws + off); off += (size_t)8192 * 1024 * 2;   // ~72MB
    u16* attnb = xn;  // xn dead after gemm_fused

    hipMemsetAsync(gsum, 0, 16, stream);
    absmean_k<<<dim3(128, 4), 256, 0, stream>>>(Wq, Wk, Wv, Wo, gsum);
    prep_k<<<16384, 256, 0, stream>>>(x, lng, lnb, xn, ctx, ctxb,
                                      Wq, Wk, Wv, Wo, wtq, wtk, wtv, wto, gsum);
    gemm_fused<<<1280, 256, 0, stream>>>(xn, ctxb, wtq, wtk, wtv, bq, bk, bv, gsum, qb_, kb, vtb);
    attn_k<<<dim3(64, 16), 256, 0, stream>>>(qb_, kb, vtb, attnb);
    gemm_o<<<512, 256, 0, stream>>>(attnb, wto, bo, gsum, x, out);
}

// Round 14
// 231.966 us; speedup vs baseline: 1.0470x; 1.0470x over previous
//
#include <hip/hip_runtime.h>
#include <hip/hip_bf16.h>

typedef __attribute__((ext_vector_type(8))) short s8x;   // 8 bf16 = 4 VGPRs (MFMA A/B frag)
typedef __attribute__((ext_vector_type(4))) float f4x;   // MFMA C/D frag
typedef unsigned short u16;
typedef unsigned int u32;

#define T_ 1024
#define TC_ 2048
#define SCLOG2E 0.1803368801111243f   // 0.125 * log2(e), folded into q-GEMM for exp2 softmax

// fine-grained waitcnt (AITER pattern): wait for all but newest N VMEM ops
#define WAIT_VM(n) asm volatile("s_waitcnt vmcnt(" #n ")" ::: "memory")

__device__ __forceinline__ u16 f2bf(float f) {
    u32 u = __float_as_uint(f);
    return (u16)((u + 0x7fffu + ((u >> 16) & 1u)) >> 16);  // RNE
}

#if defined(__has_builtin)
#if __has_builtin(__builtin_amdgcn_cvt_pk_bf16_f32)
#define HAVE_PK 1
#endif
#if __has_builtin(__builtin_amdgcn_permlane16_swap) && __has_builtin(__builtin_amdgcn_permlane32_swap)
#define HAVE_PLSWAP 1
#endif
#endif

// pack two fp32 -> two bf16 (RNE) in one u32; HW packed cvt when available
__device__ __forceinline__ u32 pack2bf(float a, float b) {
#ifdef HAVE_PK
    typedef __attribute__((ext_vector_type(2))) __bf16 bf2t;
    bf2t r = __builtin_amdgcn_cvt_pk_bf16_f32(a, b);
    u32 u;
    __builtin_memcpy(&u, &r, 4);
    return u;
#else
    return (u32)f2bf(a) | ((u32)f2bf(b) << 16);
#endif
}

// cross-lane 32/16-row swaps (gfx950)
__device__ __forceinline__ void pswap32(u32& a, u32& b) {
#ifdef HAVE_PLSWAP
    typedef __attribute__((ext_vector_type(2))) unsigned int u2x;
    u2x r = __builtin_amdgcn_permlane32_swap(a, b, false, false);
    a = r.x; b = r.y;
#else
    asm("v_permlane32_swap_b32 %0, %1" : "+v"(a), "+v"(b));
#endif
}
__device__ __forceinline__ void pswap16(u32& a, u32& b) {
#ifdef HAVE_PLSWAP
    typedef __attribute__((ext_vector_type(2))) unsigned int u2x;
    u2x r = __builtin_amdgcn_permlane16_swap(a, b, false, false);
    a = r.x; b = r.y;
#else
    asm("v_permlane16_swap_b32 %0, %1" : "+v"(a), "+v"(b));
#endif
}

// async global->LDS, 16B per lane; LDS dst is wave-uniform base + lane*16
__device__ __forceinline__ void gload16(const void* g, void* l) {
    __builtin_amdgcn_global_load_lds((const __attribute__((address_space(1))) u32*)g,
                                     (__attribute__((address_space(3))) u32*)l, 16, 0, 0);
}

// ---- gamma = mean(|W|), 4 weights in one launch ----------------------------
__global__ __launch_bounds__(256) void absmean_k(const float* __restrict__ W0, const float* __restrict__ W1,
                                                 const float* __restrict__ W2, const float* __restrict__ W3,
                                                 float* __restrict__ gsum) {
    int wi = blockIdx.y;
    const float* W = (wi == 0) ? W0 : (wi == 1) ? W1 : (wi == 2) ? W2 : W3;
    const int n4 = (1024 * 1024) / 4;
    float s = 0.f;
    int stride = gridDim.x * blockDim.x;
    for (int i = blockIdx.x * blockDim.x + threadIdx.x; i < n4; i += stride) {
        float4 v = ((const float4*)W)[i];
        s += fabsf(v.x) + fabsf(v.y) + fabsf(v.z) + fabsf(v.w);
    }
#pragma unroll
    for (int off = 32; off; off >>= 1) s += __shfl_down(s, off, 64);
    __shared__ float ps[4];
    if ((threadIdx.x & 63) == 0) ps[threadIdx.x >> 6] = s;
    __syncthreads();
    if (threadIdx.x == 0) atomicAdd(gsum + wi, ps[0] + ps[1] + ps[2] + ps[3]);
}

// ---- merged prep: LN(x)->xn | ctx->bf16 | ternary quantize (one launch) ----
__global__ __launch_bounds__(256) void prep_k(
        const float* __restrict__ x, const float* __restrict__ lng, const float* __restrict__ lnb,
        u16* __restrict__ xn,
        const float* __restrict__ ctx, u16* __restrict__ ctxb,
        const float* __restrict__ W0, const float* __restrict__ W1,
        const float* __restrict__ W2, const float* __restrict__ W3,
        u16* __restrict__ D0, u16* __restrict__ D1, u16* __restrict__ D2, u16* __restrict__ D3,
        const float* __restrict__ gsum) {
    __shared__ float ps[8];
    int bx = blockIdx.x, t = threadIdx.x;
    if (bx < 4096) {                      // LayerNorm row bx
        int row = bx;
        float4 xv = ((const float4*)(x + (long)row * 1024))[t];
        float s = xv.x + xv.y + xv.z + xv.w;
        float s2 = xv.x * xv.x + xv.y * xv.y + xv.z * xv.z + xv.w * xv.w;
#pragma unroll
        for (int off = 32; off; off >>= 1) { s += __shfl_down(s, off, 64); s2 += __shfl_down(s2, off, 64); }
        if ((t & 63) == 0) { ps[t >> 6] = s; ps[4 + (t >> 6)] = s2; }
        __syncthreads();
        float S = ps[0] + ps[1] + ps[2] + ps[3];
        float S2 = ps[4] + ps[5] + ps[6] + ps[7];
        float mu = S * (1.f / 1024.f);
        float var = S2 * (1.f / 1024.f) - mu * mu;
        float rstd = rsqrtf(var + 1e-5f);
        float4 gv = ((const float4*)lng)[t];
        float4 bv = ((const float4*)lnb)[t];
        uint2 o;
        o.x = pack2bf((xv.x - mu) * rstd * gv.x + bv.x, (xv.y - mu) * rstd * gv.y + bv.y);
        o.y = pack2bf((xv.z - mu) * rstd * gv.z + bv.z, (xv.w - mu) * rstd * gv.w + bv.w);
        ((uint2*)(xn + (long)row * 1024))[t] = o;
    } else if (bx < 12288) {              // cast context
        int i = (bx - 4096) * 256 + t;
        float4 v = ((const float4*)ctx)[i];
        uint2 o = {pack2bf(v.x, v.y), pack2bf(v.z, v.w)};
        ((uint2*)ctxb)[i] = o;
    } else {                              // ternary quantize
        int wi = (bx - 12288) >> 10;
        const float* W = (wi == 0) ? W0 : (wi == 1) ? W1 : (wi == 2) ? W2 : W3;
        u16* D = (wi == 0) ? D0 : (wi == 1) ? D1 : (wi == 2) ? D2 : D3;
        float inv = 1.0f / (gsum[wi] * (1.0f / 1048576.0f) + 1e-5f);
        int i = ((bx - 12288) & 1023) * 256 + t;
        float4 wv = ((const float4*)W)[i];
        uint2 o;
        o.x = pack2bf(fminf(1.f, fmaxf(-1.f, rintf(wv.x * inv))),
                      fminf(1.f, fmaxf(-1.f, rintf(wv.y * inv))));
        o.y = pack2bf(fminf(1.f, fmaxf(-1.f, rintf(wv.z * inv))),
                      fminf(1.f, fmaxf(-1.f, rintf(wv.w * inv))));
        ((uint2*)D)[i] = o;
    }
}

// ---- uber GEMM v10 (best): BK=64, 2x32KB dbuf, 16 unrolled steps -----------
__global__ __launch_bounds__(256) void gemm_fused(
        const u16* __restrict__ xn, const u16* __restrict__ ctxb,
        const u16* __restrict__ wtq, const u16* __restrict__ wtk, const u16* __restrict__ wtv,
        const float* __restrict__ bq, const float* __restrict__ bk, const float* __restrict__ bv,
        const float* __restrict__ gsum,
        u16* __restrict__ qb, u16* __restrict__ kb, u16* __restrict__ vtb) {
    __shared__ __align__(16) char smem[65536];   // 2 x (A0 8K|A1 8K|B0 8K|B1 8K); reused as 32K C^T tile
    int tid = threadIdx.x;
    int w = tid >> 6, l = tid & 63, lq = l & 15, lh = l >> 4;
    int wm = (w >> 1) * 64, wn = (w & 1) * 64;
    int bx = blockIdx.x;
    int xcd = bx & 7;
    int prob, m0, n0, gidx;
    const u16 *A, *Wt;
    const float* bias;
    float sc;
    if (bx < 256) {
        int local = bx >> 3;              // 0..31
        prob = 0; A = xn; Wt = wtq; bias = bq; sc = SCLOG2E; gidx = 0;
        m0 = (xcd * 4 + (local & 3)) * 128;
        n0 = (local >> 2) * 128;
    } else {
        int b = bx - 256;                 // 0..1023
        int local3 = b >> 3;              // 0..127
        int kv = local3 & 1;              // k/v alternate -> share A-tile in L2
        int idx = local3 >> 1;            // 0..63
        prob = 1 + kv; A = ctxb;
        Wt = kv ? wtv : wtk; bias = kv ? bv : bk; sc = 1.0f; gidx = 1 + kv;
        m0 = (xcd * 8 + (idx & 7)) * 128;
        n0 = (idx >> 3) * 128;
    }
    int sp = tid >> 3, ss = tid & 7;
    int st = ss ^ (sp & 7);
    int r0 = sp * 2 + (st >> 2), c0 = st & 3;
    const u16* Ag0 = A + (long)(m0 + r0) * 1024 + c0 * 8;
    const u16* Ag1 = Ag0 + 64 * 1024;
    const u16* Bg0 = Wt + (long)(n0 + r0) * 1024 + c0 * 8;
    const u16* Bg1 = Bg0 + 64 * 1024;
    int aoff[4], boff[4];
#pragma unroll
    for (int i = 0; i < 4; i++) {
        int ar = wm + i * 16 + lq, ap = ar >> 1;
        aoff[i] = ap * 128 + (((((ar & 1) << 2) | lh) ^ (ap & 7)) * 16);
        int br = wn + i * 16 + lq, bp = br >> 1;
        boff[i] = bp * 128 + (((((br & 1) << 2) | lh) ^ (bp & 7)) * 16);
    }
    f4x acc[4][4] = {};
    // stage one BK=64 tile (32KB = 8 gload16): A halves at 0/8K, B at 16K/24K
#define STAGE_G(kt, buf)                                                   \
    {                                                                      \
        char* Ad = smem + (buf) * 32768;                                   \
        gload16(Ag0 + (kt) * 64, Ad + tid * 16);                           \
        gload16(Ag1 + (kt) * 64, Ad + 4096 + tid * 16);                    \
        gload16(Ag0 + (kt) * 64 + 32, Ad + 8192 + tid * 16);               \
        gload16(Ag1 + (kt) * 64 + 32, Ad + 12288 + tid * 16);              \
        gload16(Bg0 + (kt) * 64, Ad + 16384 + tid * 16);                   \
        gload16(Bg1 + (kt) * 64, Ad + 20480 + tid * 16);                   \
        gload16(Bg0 + (kt) * 64 + 32, Ad + 24576 + tid * 16);              \
        gload16(Bg1 + (kt) * 64 + 32, Ad + 28672 + tid * 16);              \
    }
    STAGE_G(0, 0);
    STAGE_G(1, 1);
#pragma unroll
    for (int kt = 0; kt < 16; kt++) {      // fully unrolled: kt compile-time
        if (kt < 15) { WAIT_VM(8); } else { WAIT_VM(0); }
        __builtin_amdgcn_s_barrier();
        const char* Ac = smem + (kt & 1) * 32768;
        const char* Bc = Ac + 16384;
        s8x af[2][4], bfr[2][4];
#pragma unroll
        for (int h = 0; h < 2; h++)
#pragma unroll
            for (int i = 0; i < 4; i++) {
                af[h][i] = *(const s8x*)(Ac + h * 8192 + aoff[i]);
                bfr[h][i] = *(const s8x*)(Bc + h * 8192 + boff[i]);
            }
#pragma unroll
        for (int h = 0; h < 2; h++)
#pragma unroll
            for (int i = 0; i < 4; i++)
#pragma unroll
                for (int j = 0; j < 4; j++)
                    acc[i][j] = __builtin_amdgcn_mfma_f32_16x16x32_bf16(af[h][i], bfr[h][j], acc[i][j], 0, 0, 0);
        __builtin_amdgcn_s_barrier();      // all waves done reading buf kt&1
        if (kt + 2 < 16) STAGE_G(kt + 2, kt & 1);
    }
    float gamma = gsum[gidx] * (1.0f / 1048576.0f) * sc;
    if (prob < 2) {
        u16* outq = (prob == 0) ? qb : kb;
        int tshift = (prob == 0) ? 10 : 11;
        int tmask = (1 << tshift) - 1;
#pragma unroll
        for (int i = 0; i < 4; i++) {
            int gr = m0 + wm + i * 16 + lh * 4;
#pragma unroll
            for (int j = 0; j < 4; j++) {
                int gc = n0 + wn + j * 16 + lq;
                float bb = bias[gc] * sc;
                int h = gc >> 6, d = gc & 63;
#pragma unroll
                for (int r = 0; r < 4; r++) {
                    int row = gr + r;
                    int bidx = row >> tshift, tt = row & tmask;
                    outq[((((long)(bidx * 16 + h)) << tshift) + tt) * 64 + d] = f2bf(acc[i][j][r] * gamma + bb);
                }
            }
        }
    } else {
        // V^T epilogue: C tile -> LDS [col][tt] (swizzled) -> coalesced b128 stores
        __syncthreads();
        char* Ct = smem;
#pragma unroll
        for (int i = 0; i < 4; i++) {
            int tt = wm + i * 16 + lh * 4;
#pragma unroll
            for (int j = 0; j < 4; j++) {
                int c = wn + j * 16 + lq;
                float bb = bias[n0 + c];
                uint2 pk;
                pk.x = pack2bf(acc[i][j][0] * gamma + bb, acc[i][j][1] * gamma + bb);
                pk.y = pack2bf(acc[i][j][2] * gamma + bb, acc[i][j][3] * gamma + bb);
                int slot = (tt >> 3) ^ (c & 15);
                *(uint2*)(Ct + c * 256 + slot * 16 + (tt & 7) * 2) = pk;
            }
        }
        __syncthreads();
        int bb2 = m0 >> 11, t0 = m0 & 2047;
#pragma unroll
        for (int it = 0; it < 8; it++) {
            int e = it * 256 + tid;
            int c = e >> 4, ch = e & 15;
            int slot = ch ^ (c & 15);
            s8x v = *(const s8x*)(Ct + c * 256 + slot * 16);
            int gcg = n0 + c;
            int h = gcg >> 6, d = gcg & 63;
            *(s8x*)(vtb + ((long)((bb2 * 16 + h) * 64 + d)) * TC_ + t0 + ch * 8) = v;
        }
    }
}

// ---- O GEMM v10 (best): out = x + attn @ WoT + bo, BK=64 2x24KB ------------
__global__ __launch_bounds__(256) void gemm_o(const u16* __restrict__ A, const u16* __restrict__ Wt,
                                              const float* __restrict__ bias, const float* __restrict__ gsum,
                                              const float* __restrict__ residual, float* __restrict__ outr) {
    __shared__ __align__(16) char smem[49152];   // 2 x (A0 8K|A1 8K|B0 4K|B1 4K)
    int tid = threadIdx.x;
    int w = tid >> 6, l = tid & 63, lq = l & 15, lh = l >> 4;
    int wm = (w >> 1) * 64, wn = (w & 1) * 32;
    int bx = blockIdx.x;
    int xcd = bx & 7, local = bx >> 3;
    int m0 = (xcd * 4 + (local & 3)) * 128;
    int n0 = (local >> 2) * 64;
    int sp = tid >> 3, ss = tid & 7;
    int st = ss ^ (sp & 7);
    int r0 = sp * 2 + (st >> 2), c0 = st & 3;
    const u16* Ag0 = A + (long)(m0 + r0) * 1024 + c0 * 8;
    const u16* Ag1 = Ag0 + 64 * 1024;
    const u16* Bg0 = Wt + (long)(n0 + r0) * 1024 + c0 * 8;
    int aoff[4], boff[2];
#pragma unroll
    for (int i = 0; i < 4; i++) {
        int ar = wm + i * 16 + lq, ap = ar >> 1;
        aoff[i] = ap * 128 + (((((ar & 1) << 2) | lh) ^ (ap & 7)) * 16);
    }
#pragma unroll
    for (int j = 0; j < 2; j++) {
        int br = wn + j * 16 + lq, bp = br >> 1;
        boff[j] = bp * 128 + (((((br & 1) << 2) | lh) ^ (bp & 7)) * 16);
    }
    f4x acc[4][2] = {};
#define STAGE_O(kt, buf)                                                   \
    {                                                                      \
        char* Ad = smem + (buf) * 24576;                                   \
        gload16(Ag0 + (kt) * 64, Ad + tid * 16);                           \
        gload16(Ag1 + (kt) * 64, Ad + 4096 + tid * 16);                    \
        gload16(Ag0 + (kt) * 64 + 32, Ad + 8192 + tid * 16);               \
        gload16(Ag1 + (kt) * 64 + 32, Ad + 12288 + tid * 16);              \
        gload16(Bg0 + (kt) * 64, Ad + 16384 + tid * 16);                   \
        gload16(Bg0 + (kt) * 64 + 32, Ad + 20480 + tid * 16);              \
    }
    STAGE_O(0, 0);
    STAGE_O(1, 1);
#pragma unroll
    for (int kt = 0; kt < 16; kt++) {
        if (kt < 15) { WAIT_VM(6); } else { WAIT_VM(0); }
        __builtin_amdgcn_s_barrier();
        const char* Ac = smem + (kt & 1) * 24576;
        const char* Bc = Ac + 16384;
        s8x af[2][4], bfr[2][2];
#pragma unroll
        for (int h = 0; h < 2; h++) {
#pragma unroll
            for (int i = 0; i < 4; i++) af[h][i] = *(const s8x*)(Ac + h * 8192 + aoff[i]);
#pragma unroll
            for (int j = 0; j < 2; j++) bfr[h][j] = *(const s8x*)(Bc + h * 4096 + boff[j]);
        }
#pragma unroll
        for (int h = 0; h < 2; h++)
#pragma unroll
            for (int i = 0; i < 4; i++)
#pragma unroll
                for (int j = 0; j < 2; j++)
                    acc[i][j] = __builtin_amdgcn_mfma_f32_16x16x32_bf16(af[h][i], bfr[h][j], acc[i][j], 0, 0, 0);
        __builtin_amdgcn_s_barrier();
        if (kt + 2 < 16) STAGE_O(kt + 2, kt & 1);
    }
    float gamma = gsum[3] * (1.0f / 1048576.0f);
#pragma unroll
    for (int i = 0; i < 4; i++) {
        int gr = m0 + wm + i * 16 + lh * 4;
#pragma unroll
        for (int j = 0; j < 2; j++) {
            int gc = n0 + wn + j * 16 + lq;
            float bb = bias[gc];
#pragma unroll
            for (int r = 0; r < 4; r++) {
                long idx = (long)(gr + r) * 1024 + gc;
                outr[idx] = residual[idx] + acc[i][j][r] * gamma + bb;
            }
        }
    }
}

// ---- flash attention v8 (session-best; v14 TLP split REVERTED: +40%
//      occupancy but doubled compulsory KV LDS traffic -> net -2%. v8 =
//      cross-iteration pipeline, 4 x 16KB K/V bufs, stage-ahead-3, counted
//      WAIT_VM(4), in-register P via cvt_pk + permlane, rowsum via MFMA) -----
__global__ __launch_bounds__(256, 2) void attn_k(const u16* __restrict__ qh, const u16* __restrict__ kh,
                                                 const u16* __restrict__ vth, u16* __restrict__ attn) {
    __shared__ __align__(16) char smem[65536];   // 4 x (K 8K | V 8K)
    int tid = threadIdx.x, w = tid >> 6, l = tid & 63, lq = l & 15, lh = l >> 4;
    int bh = blockIdx.x, q0 = blockIdx.y * 128;
    const u16* qp = qh + ((long)bh * T_ + q0) * 64;
    // ---- prologue: Q tile (16KB, swizzled) into buf0, read qf --------------
#pragma unroll
    for (int i = 0; i < 4; i++) {
        int cid = i * 256 + tid;
        int r = cid >> 3, c = (cid & 7) ^ (r & 7);
        gload16(qp + r * 64 + c * 8, smem + cid * 16);
    }
    __syncthreads();                     // vmcnt(0): Q arrived
    s8x qf[2][2];                        // B-operand: Q[q=w*32+qb*16+lq][d=dh*32+lh*8+j]
#pragma unroll
    for (int qb = 0; qb < 2; qb++)
#pragma unroll
        for (int dh = 0; dh < 2; dh++) {
            int qrow = w * 32 + qb * 16 + lq;
            int ch = (dh * 4 + lh) ^ (qrow & 7);
            qf[qb][dh] = *(const s8x*)(smem + qrow * 128 + ch * 16);
        }
    __syncthreads();                     // lgkm(0): Q reads done before overwrite
    // ---- staging pointers (advance per tile) -------------------------------
    int sr = tid >> 3, sc = (tid & 7) ^ ((tid >> 3) & 7);
    const u16* kgA = kh + (long)bh * TC_ * 64 + sr * 64 + sc * 8;
    const u16* kgB = kgA + 2048;                       // +32 rows
    const u16* vgA = vth + (long)bh * 64 * TC_ + (long)sr * TC_ + sc * 8;
    const u16* vgB = vgA + 32 * TC_;
    // ---- LDS read bases: everything else is a 16-bit immediate -------------
    const char* pA = smem + lq * 128 + ((lh ^ (lq & 7)) * 16);
    const char* pB = smem + lq * 128 + (((4 + lh) ^ (lq & 7)) * 16);
#define STAGE4(buf)                                              \
    {                                                            \
        char* Kb = smem + (buf) * 16384;                         \
        gload16(kgA, Kb + tid * 16);                             \
        gload16(kgB, Kb + 4096 + tid * 16);                      \
        gload16(vgA, Kb + 8192 + tid * 16);                      \
        gload16(vgB, Kb + 12288 + tid * 16);                     \
        kgA += 4096; kgB += 4096; vgA += 64; vgB += 64;          \
    }
    // softmax of one qb: z -> two bf16 A-frags via cvt_pk + permlane swaps
#define SM1(ZA, qb, PF0, PF1)                                                                              \
    s8x PF0, PF1;                                                                                          \
    {                                                                                                      \
        u32 w00 = pack2bf(__builtin_amdgcn_exp2f(ZA[qb][0][0]), __builtin_amdgcn_exp2f(ZA[qb][0][1]));     \
        u32 w01 = pack2bf(__builtin_amdgcn_exp2f(ZA[qb][0][2]), __builtin_amdgcn_exp2f(ZA[qb][0][3]));     \
        u32 w10 = pack2bf(__builtin_amdgcn_exp2f(ZA[qb][1][0]), __builtin_amdgcn_exp2f(ZA[qb][1][1]));     \
        u32 w11 = pack2bf(__builtin_amdgcn_exp2f(ZA[qb][1][2]), __builtin_amdgcn_exp2f(ZA[qb][1][3]));     \
        u32 w20 = pack2bf(__builtin_amdgcn_exp2f(ZA[qb][2][0]), __builtin_amdgcn_exp2f(ZA[qb][2][1]));     \
        u32 w21 = pack2bf(__builtin_amdgcn_exp2f(ZA[qb][2][2]), __builtin_amdgcn_exp2f(ZA[qb][2][3]));     \
        u32 w30 = pack2bf(__builtin_amdgcn_exp2f(ZA[qb][3][0]), __builtin_amdgcn_exp2f(ZA[qb][3][1]));     \
        u32 w31 = pack2bf(__builtin_amdgcn_exp2f(ZA[qb][3][2]), __builtin_amdgcn_exp2f(ZA[qb][3][3]));     \
        u32 a0w = w00, a1w = w10; pswap32(a0w, a1w); pswap16(a0w, a1w);                                    \
        u32 b0w = w01, b1w = w11; pswap32(b0w, b1w); pswap16(b0w, b1w);                                    \
        u32 c0w = w20, c1w = w30; pswap32(c0w, c1w); pswap16(c0w, c1w);                                    \
        u32 d0w = w21, d1w = w31; pswap32(d0w, d1w); pswap16(d0w, d1w);                                    \
        u32 pw0[4] = {a0w, b0w, a1w, b1w};                                                                 \
        u32 pw1[4] = {c0w, d0w, c1w, d1w};                                                                 \
        __builtin_memcpy(&PF0, pw0, 16);                                                                   \
        __builtin_memcpy(&PF1, pw1, 16);                                                                   \
    }
    // one pipelined step: consume tile kt (V buf JB, scores ZC) + QK tile kt+1 (K buf KB -> ZN)
#define SUBITER(JB, KB, SB, ZC, ZN, WN, DOSTAGE)                                                           \
    {                                                                                                      \
        WAIT_VM(WN);                                                                                       \
        __builtin_amdgcn_s_barrier();                                                                      \
        if (DOSTAGE) STAGE4(SB);                                                                           \
        s8x a0_[4], a1_[4], v0_[4], v1_[4];                                                                \
        _Pragma("unroll") for (int ni = 0; ni < 4; ni++) {                                                 \
            a0_[ni] = *(const s8x*)(pA + (KB) * 16384 + ni * 2048);                                        \
            a1_[ni] = *(const s8x*)(pB + (KB) * 16384 + ni * 2048);                                        \
        }                                                                                                  \
        _Pragma("unroll") for (int nd = 0; nd < 4; nd++) {                                                 \
            v0_[nd] = *(const s8x*)(pA + (JB) * 16384 + 8192 + nd * 2048);                                 \
            v1_[nd] = *(const s8x*)(pB + (JB) * 16384 + 8192 + nd * 2048);                                 \
        }                                                                                                  \
        SM1(ZC, 0, pfa0, pfa1)                                                                             \
        __builtin_amdgcn_s_setprio(1);                                                                     \
        _Pragma("unroll") for (int ni = 0; ni < 4; ni++) {                                                 \
            _Pragma("unroll") for (int qb = 0; qb < 2; qb++) {                                             \
                f4x zz = {0.f, 0.f, 0.f, 0.f};                                                             \
                zz = __builtin_amdgcn_mfma_f32_16x16x32_bf16(a0_[ni], qf[qb][0], zz, 0, 0, 0);             \
                zz = __builtin_amdgcn_mfma_f32_16x16x32_bf16(a1_[ni], qf[qb][1], zz, 0, 0, 0);             \
                ZN[qb][ni] = zz;                                                                           \
            }                                                                                              \
        }                                                                                                  \
        __builtin_amdgcn_s_setprio(0);                                                                     \
        SM1(ZC, 1, pfb0, pfb1)                                                                             \
        __builtin_amdgcn_s_setprio(1);                                                                     \
        lrun[0] = __builtin_amdgcn_mfma_f32_16x16x32_bf16(pfa0, ones, lrun[0], 0, 0, 0);                   \
        lrun[0] = __builtin_amdgcn_mfma_f32_16x16x32_bf16(pfa1, ones, lrun[0], 0, 0, 0);                   \
        lrun[1] = __builtin_amdgcn_mfma_f32_16x16x32_bf16(pfb0, ones, lrun[1], 0, 0, 0);                   \
        lrun[1] = __builtin_amdgcn_mfma_f32_16x16x32_bf16(pfb1, ones, lrun[1], 0, 0, 0);                   \
        _Pragma("unroll") for (int nd = 0; nd < 4; nd++) {                                                 \
            oacc[0][nd] = __builtin_amdgcn_mfma_f32_16x16x32_bf16(pfa0, v0_[nd], oacc[0][nd], 0, 0, 0);    \
            oacc[0][nd] = __builtin_amdgcn_mfma_f32_16x16x32_bf16(pfa1, v1_[nd], oacc[0][nd], 0, 0, 0);    \
            oacc[1][nd] = __builtin_amdgcn_mfma_f32_16x16x32_bf16(pfb0, v0_[nd], oacc[1][nd], 0, 0, 0);    \
            oacc[1][nd] = __builtin_amdgcn_mfma_f32_16x16x32_bf16(pfb1, v1_[nd], oacc[1][nd], 0, 0, 0);    \
        }                                                                                                  \
        __builtin_amdgcn_s_setprio(0);                                                                     \
    }
    const s8x ones = {16256, 16256, 16256, 16256, 16256, 16256, 16256, 16256};  // bf16 1.0 x8
    f4x z0[2][4], z1[2][4];
    f4x oacc[2][4] = {};
    f4x lrun[2] = {};
    // ---- pipeline fill: stage tiles 0..2, QK(0) -> z0 ----------------------
    STAGE4(0); STAGE4(1); STAGE4(2);
    WAIT_VM(8);                          // tile 0 arrived (tiles 1,2 in flight)
    __builtin_amdgcn_s_barrier();
    {
        s8x a0_[4], a1_[4];
#pragma unroll
        for (int ni = 0; ni < 4; ni++) {
            a0_[ni] = *(const s8x*)(pA + ni * 2048);
            a1_[ni] = *(const s8x*)(pB + ni * 2048);
        }
#pragma unroll
        for (int ni = 0; ni < 4; ni++)
#pragma unroll
            for (int qb = 0; qb < 2; qb++) {
                f4x zz = {0.f, 0.f, 0.f, 0.f};
                zz = __builtin_amdgcn_mfma_f32_16x16x32_bf16(a0_[ni], qf[qb][0], zz, 0, 0, 0);
                zz = __builtin_amdgcn_mfma_f32_16x16x32_bf16(a1_[ni], qf[qb][1], zz, 0, 0, 0);
                z0[qb][ni] = zz;
            }
    }
    // ---- main loop: kt = 0..27 (stage kt+3, QK kt+1, PV kt) ----------------
    for (int t = 0; t < 7; t++) {
        SUBITER(0, 1, 3, z0, z1, 4, true)
        SUBITER(1, 2, 0, z1, z0, 4, true)
        SUBITER(2, 3, 1, z0, z1, 4, true)
        SUBITER(3, 0, 2, z1, z0, 4, true)
    }
    // ---- drain: kt = 28,29,30 then PV(31) ----------------------------------
    SUBITER(0, 1, 3, z0, z1, 4, true)    // kt=28: stage tile31 -> buf3
    SUBITER(1, 2, 0, z1, z0, 4, false)   // kt=29
    SUBITER(2, 3, 1, z0, z1, 0, false)   // kt=30: drain all staging
    {                                     // kt=31: softmax + PV only (tile in buf3)
        s8x v0_[4], v1_[4];
#pragma unroll
        for (int nd = 0; nd < 4; nd++) {
            v0_[nd] = *(const s8x*)(pA + 3 * 16384 + 8192 + nd * 2048);
            v1_[nd] = *(const s8x*)(pB + 3 * 16384 + 8192 + nd * 2048);
        }
        SM1(z1, 0, pfa0, pfa1)
        SM1(z1, 1, pfb0, pfb1)
        __builtin_amdgcn_s_setprio(1);
        lrun[0] = __builtin_amdgcn_mfma_f32_16x16x32_bf16(pfa0, ones, lrun[0], 0, 0, 0);
        lrun[0] = __builtin_amdgcn_mfma_f32_16x16x32_bf16(pfa1, ones, lrun[0], 0, 0, 0);
        lrun[1] = __builtin_amdgcn_mfma_f32_16x16x32_bf16(pfb0, ones, lrun[1], 0, 0, 0);
        lrun[1] = __builtin_amdgcn_mfma_f32_16x16x32_bf16(pfb1, ones, lrun[1], 0, 0, 0);
#pragma unroll
        for (int nd = 0; nd < 4; nd++) {
            oacc[0][nd] = __builtin_amdgcn_mfma_f32_16x16x32_bf16(pfa0, v0_[nd], oacc[0][nd], 0, 0, 0);
            oacc[0][nd] = __builtin_amdgcn_mfma_f32_16x16x32_bf16(pfa1, v1_[nd], oacc[0][nd], 0, 0, 0);
            oacc[1][nd] = __builtin_amdgcn_mfma_f32_16x16x32_bf16(pfb0, v0_[nd], oacc[1][nd], 0, 0, 0);
            oacc[1][nd] = __builtin_amdgcn_mfma_f32_16x16x32_bf16(pfb1, v1_[nd], oacc[1][nd], 0, 0, 0);
        }
        __builtin_amdgcn_s_setprio(0);
    }
    // ---- epilogue ----------------------------------------------------------
    int b = bh >> 4, h = bh & 15;
#pragma unroll
    for (int qb = 0; qb < 2; qb++)
#pragma unroll
        for (int r = 0; r < 4; r++) {
            int q = q0 + w * 32 + qb * 16 + lh * 4 + r;
            float rcp = 1.f / lrun[qb][r];
#pragma unroll
            for (int nd = 0; nd < 4; nd++)
                attn[((long)(b * T_ + q)) * 1024 + h * 64 + nd * 16 + lq] = f2bf(oacc[qb][nd][r] * rcp);
        }
}

extern "C" void kernel_launch(void* const* d_in, const int* in_sizes, int n_in,
                              void* d_out, int out_size, void* d_ws, size_t ws_size,
                              hipStream_t stream) {
    const float* x   = (const float*)d_in[0];
    const float* ctx = (const float*)d_in[1];
    const float* Wq  = (const float*)d_in[2];
    const float* bq  = (const float*)d_in[3];
    const float* Wk  = (const float*)d_in[4];
    const float* bk  = (const float*)d_in[5];
    const float* Wv  = (const float*)d_in[6];
    const float* bv  = (const float*)d_in[7];
    const float* Wo  = (const float*)d_in[8];
    const float* bo  = (const float*)d_in[9];
    const float* lng = (const float*)d_in[10];
    const float* lnb = (const float*)d_in[11];
    float* out = (float*)d_out;

    char* ws = (char*)d_ws;
    float* gsum = (float*)ws;
    size_t off = 256;
    u16* wtq  = (u16*)(ws + off); off += (size_t)1024 * 1024 * 2;
    u16* wtk  = (u16*)(ws + off); off += (size_t)1024 * 1024 * 2;
    u16* wtv  = (u16*)(ws + off); off += (size_t)1024 * 1024 * 2;
    u16* wto  = (u16*)(ws + off); off += (size_t)1024 * 1024 * 2;
    u16* ctxb = (u16*)(ws + off); off += (size_t)8192 * 1024 * 2;
    u16* xn   = (u16*)(ws + off); off += (size_t)4096 * 1024 * 2;   // reused as attn out
    u16* qb_  = (u16*)(ws + off); off += (size_t)4096 * 1024 * 2;
    u16* kb   = (u16*)(ws + off); off += (size_t)8192 * 1024 * 2;
    u16* vtb  = (u16*)(ws + off); off += (size_t)8192 * 1024 * 2;   // ~72MB
    u16* attnb = xn;  // xn dead after gemm_fused

    hipMemsetAsync(gsum, 0, 16, stream);
    absmean_k<<<dim3(128, 4), 256, 0, stream>>>(Wq, Wk, Wv, Wo, gsum);
    prep_k<<<16384, 256, 0, stream>>>(x, lng, lnb, xn, ctx, ctxb,
                                      Wq, Wk, Wv, Wo, wtq, wtk, wtv, wto, gsum);
    gemm_fused<<<1280, 256, 0, stream>>>(xn, ctxb, wtq, wtk, wtv, bq, bk, bv, gsum, qb_, kb, vtb);
    attn_k<<<dim3(64, 8), 256, 0, stream>>>(qb_, kb, vtb, attnb);
    gemm_o<<<512, 256, 0, stream>>>(attnb, wto, bo, gsum, x, out);
}